// Round 1
// baseline (963.297 us; speedup 1.0000x reference)
//
#include <hip/hip_runtime.h>
#include <hip/hip_cooperative_groups.h>

namespace cg = cooperative_groups;

#define NN    2048
#define NBLK  256
#define NTHR  256
#define MAXIT 50
#define TOLF  1e-6f
#define EPSF  1e-10f

// ws layout (floats):
//   [0,2048)      s      sorted scores (descending)
//   [2048,4096)   lab    labels = 2^y_true - 1
//   [4096,6144)   r      row scaling vector
//   [6144,8192)   c      col scaling vector
//   [8192,8256)   g_dev  (as unsigned) per-iteration max |colsum-1|
//   [8256]        g_dcg
//   [8257]        g_idcg

__global__ __launch_bounds__(NTHR, 1) void sndcg_kernel(
    const float* __restrict__ y_pred, const float* __restrict__ y_true,
    float* __restrict__ out, float* __restrict__ ws)
{
    cg::grid_group grid = cg::this_grid();
    const int T = threadIdx.x;
    const int B = blockIdx.x;
    const int G = B * NTHR + T;
    const int wave = T >> 6;     // 0..3
    const int lane = T & 63;

    float*    s     = ws;
    float*    lab   = ws + 2048;
    float*    r     = ws + 4096;
    float*    c     = ws + 6144;
    unsigned* g_dev = (unsigned*)(ws + 8192);
    float*    g_dcg  = ws + 8256;
    float*    g_idcg = ws + 8257;

    __shared__ float lds_s[NN];
    __shared__ float lds_p[NN];
    __shared__ float lds_w[NN];

    // ---------------- step 1: labels + init scalars ----------------
    if (G < NN) {
        lab[G] = exp2f(y_true[G]) - 1.0f;   // gain transform
        r[G]   = 1.0f;
        c[G]   = 1.0f;
    } else if (G < NN + 64) {
        g_dev[G - NN] = 0u;
    } else if (G == NN + 64) {
        *g_dcg = 0.0f;
    } else if (G == NN + 65) {
        *g_idcg = 0.0f;
    }
    grid.sync();

    // ---------------- step 2: rank-count sorts ----------------
    // Descending rank: #(v_j > v_i) + #(v_j == v_i && j < i)  -> bijection.
    if (G < NN) {
        float v = y_pred[G];
        int rank = 0;
        const float4* y4 = (const float4*)y_pred;
        for (int q = 0; q < NN / 4; ++q) {
            float4 w4 = y4[q];
            int j = q * 4;
            rank += (w4.x > v) || ((w4.x == v) && (j     < G));
            rank += (w4.y > v) || ((w4.y == v) && (j + 1 < G));
            rank += (w4.z > v) || ((w4.z == v) && (j + 2 < G));
            rank += (w4.w > v) || ((w4.w == v) && (j + 3 < G));
        }
        s[rank] = v;
    } else if (G < 2 * NN) {
        int e = G - NN;
        float lv = lab[e];
        int rank = 0;
        const float4* l4 = (const float4*)lab;
        for (int q = 0; q < NN / 4; ++q) {
            float4 w4 = l4[q];
            int j = q * 4;
            rank += (w4.x > lv) || ((w4.x == lv) && (j     < e));
            rank += (w4.y > lv) || ((w4.y == lv) && (j + 1 < e));
            rank += (w4.z > lv) || ((w4.z == lv) && (j + 2 < e));
            rank += (w4.w > lv) || ((w4.w == lv) && (j + 3 < e));
        }
        // IDCG contribution: sorted-desc labels / log2(pos+2)
        atomicAdd(g_idcg, lv / log2f((float)(rank + 2)));
    }
    grid.sync();

    // ---------------- load static LDS ----------------
    for (int idx = T; idx < NN; idx += NTHR) {
        lds_s[idx] = s[idx];
        lds_p[idx] = y_pred[idx];
        lds_w[idx] = 1.0f;   // weights for the init row-sum (c == 1)
    }
    __syncthreads();

    const int base = B * 8;   // 8 rows/cols owned per block; each wave owns 2

    // ---------------- init: row softmax  (r_i = 1 / rowsum_i) ----------------
    for (int k = 0; k < 2; ++k) {
        int i = base + wave * 2 + k;
        float si = lds_s[i];
        float partial = 0.0f;
        #pragma unroll
        for (int m = 0; m < NN / 64; ++m) {
            int j = lane + (m << 6);
            partial += __expf(-fabsf(si - lds_p[j])) * lds_w[j];
        }
        #pragma unroll
        for (int off = 32; off > 0; off >>= 1)
            partial += __shfl_xor(partial, off, 64);
        if (lane == 0) {
            r[i] = 1.0f / fmaxf(partial, EPSF);   // rowmax of dist == 0 exactly
        }
    }
    grid.sync();

    // ---------------- Sinkhorn loop ----------------
    for (int it = 1; it <= MAXIT; ++it) {
        // phase A: col sums  a_j = sum_i K_ij r_i ; update c
        for (int idx = T; idx < NN; idx += NTHR) lds_w[idx] = r[idx];
        __syncthreads();
        for (int k = 0; k < 2; ++k) {
            int j = base + wave * 2 + k;
            float pj = lds_p[j];
            float partial = 0.0f;
            #pragma unroll
            for (int m = 0; m < NN / 64; ++m) {
                int i = lane + (m << 6);
                partial += __expf(-fabsf(lds_s[i] - pj)) * lds_w[i];
            }
            #pragma unroll
            for (int off = 32; off > 0; off >>= 1)
                partial += __shfl_xor(partial, off, 64);
            if (lane == 0) {
                float cj = c[j];
                float colsum = cj * partial;        // col sum of current m
                c[j] = cj / fmaxf(colsum, EPSF);
                if (it >= 2) {                      // convergence test of m_{it-1}
                    float dev = fabsf(colsum - 1.0f);
                    atomicMax(&g_dev[it], __float_as_uint(dev));
                }
            }
        }
        grid.sync();

        bool stop = false;
        if (it >= 2) {
            unsigned db = *((volatile unsigned*)&g_dev[it]);
            stop = (__uint_as_float(db) < TOLF);    // row sums == 1 by construction
        }

        // phase B: row sums  b_i = sum_j K_ij c_j ; update r
        for (int idx = T; idx < NN; idx += NTHR) lds_w[idx] = c[idx];
        __syncthreads();
        for (int k = 0; k < 2; ++k) {
            int i = base + wave * 2 + k;
            float si = lds_s[i];
            float partial = 0.0f;
            #pragma unroll
            for (int m = 0; m < NN / 64; ++m) {
                int j = lane + (m << 6);
                partial += __expf(-fabsf(si - lds_p[j])) * lds_w[j];
            }
            #pragma unroll
            for (int off = 32; off > 0; off >>= 1)
                partial += __shfl_xor(partial, off, 64);
            if (lane == 0) {
                float ri = r[i];
                float rowsum = ri * partial;
                r[i] = ri / fmaxf(rowsum, EPSF);
            }
        }
        grid.sync();
        if (stop) break;   // uniform across grid
    }

    // ---------------- epilogue: dcg = sum_i r_i * (K (c.*lab))_i / disc_i ----
    for (int idx = T; idx < NN; idx += NTHR) lds_w[idx] = c[idx] * lab[idx];
    __syncthreads();
    for (int k = 0; k < 2; ++k) {
        int i = base + wave * 2 + k;
        float si = lds_s[i];
        float partial = 0.0f;
        #pragma unroll
        for (int m = 0; m < NN / 64; ++m) {
            int j = lane + (m << 6);
            partial += __expf(-fabsf(si - lds_p[j])) * lds_w[j];
        }
        #pragma unroll
        for (int off = 32; off > 0; off >>= 1)
            partial += __shfl_xor(partial, off, 64);
        if (lane == 0) {
            float gains = r[i] * partial / log2f((float)(i + 2));
            atomicAdd(g_dcg, gains);
        }
    }
    grid.sync();

    if (G == 0) {
        out[0] = 1.0f - (*g_dcg) / (*g_idcg);
    }
}

extern "C" void kernel_launch(void* const* d_in, const int* in_sizes, int n_in,
                              void* d_out, int out_size, void* d_ws, size_t ws_size,
                              hipStream_t stream) {
    const float* y_pred = (const float*)d_in[0];
    const float* y_true = (const float*)d_in[1];
    float* out = (float*)d_out;
    float* ws  = (float*)d_ws;

    void* args[] = {(void*)&y_pred, (void*)&y_true, (void*)&out, (void*)&ws};
    hipLaunchCooperativeKernel((void*)sndcg_kernel, dim3(NBLK), dim3(NTHR),
                               args, 0, stream);
}

// Round 2
// 199.053 us; speedup vs baseline: 4.8394x; 4.8394x over previous
//
#include <hip/hip_runtime.h>
#include <math.h>

#define NN    2048
#define NT    1024          // kernel B threads (16 waves)
#define NWAVE 16
#define MAXIT 50
#define TOLD  1e-6
#define EPSD  1e-10

// ws float layout: [0,2048) s sorted-desc scores ; [2048,4096) labp labels
// permuted into score-sorted coords ; [4096,6144) slab labels sorted desc.

// ---------------------------------------------------------------------------
// Kernel A: rank-count sorts (16 blocks x 256 = 4096 threads, ~4 us)
// ---------------------------------------------------------------------------
__global__ __launch_bounds__(256) void prep_kernel(
    const float* __restrict__ y_pred, const float* __restrict__ y_true,
    float* __restrict__ s, float* __restrict__ labp, float* __restrict__ slab)
{
    int tid = blockIdx.x * 256 + threadIdx.x;
    if (tid < NN) {
        // descending rank of y_pred[tid], ties broken by index -> bijection
        float v = y_pred[tid];
        const float4* y4 = (const float4*)y_pred;
        int rank = 0;
        for (int q = 0; q < NN / 4; ++q) {
            float4 w = y4[q]; int j = q * 4;
            rank += (w.x > v) || ((w.x == v) && (j     < tid));
            rank += (w.y > v) || ((w.y == v) && (j + 1 < tid));
            rank += (w.z > v) || ((w.z == v) && (j + 2 < tid));
            rank += (w.w > v) || ((w.w == v) && (j + 3 < tid));
        }
        s[rank]    = v;
        labp[rank] = exp2f(y_true[tid]) - 1.0f;   // label in sorted-score coords
    } else if (tid < 2 * NN) {
        // descending rank of y_true (monotone with label) -> sorted labels
        int e = tid - NN;
        float v = y_true[e];
        const float4* y4 = (const float4*)y_true;
        int rank = 0;
        for (int q = 0; q < NN / 4; ++q) {
            float4 w = y4[q]; int j = q * 4;
            rank += (w.x > v) || ((w.x == v) && (j     < e));
            rank += (w.y > v) || ((w.y == v) && (j + 1 < e));
            rank += (w.z > v) || ((w.z == v) && (j + 2 < e));
            rank += (w.w > v) || ((w.w == v) && (j + 3 < e));
        }
        slab[rank] = exp2f(v) - 1.0f;
    }
}

// ---------------------------------------------------------------------------
// Kernel B: single-block Sinkhorn via O(N) prefix-sum mat-vecs
// ---------------------------------------------------------------------------

// Inclusive prefix scan of t and u over 2048 elems (2/thread, contiguous),
// returns A_i = prefix_t(i) (inclusive) and B_i = sum_{k>i} u_k = totU - prefix_u(i).
// Uses shared wtA/wtU (16 wave totals). One __syncthreads inside.
__device__ __forceinline__ void phase_scan(
    double tv0, double tv1, double uv0, double uv1,
    double* wtA, double* wtU, int lane, int wave,
    double& A0, double& A1, double& B0, double& B1)
{
    double tp = tv0 + tv1, up = uv0 + uv1;
    double xt = tp, xu = up;
    #pragma unroll
    for (int d = 1; d < 64; d <<= 1) {
        double yt = __shfl_up(xt, (unsigned)d, 64);
        double yu = __shfl_up(xu, (unsigned)d, 64);
        if (lane >= d) { xt += yt; xu += yu; }
    }
    if (lane == 63) { wtA[wave] = xt; wtU[wave] = xu; }
    double baseT = xt - tp, baseU = xu - up;   // exclusive pair-prefix in wave
    __syncthreads();
    double offT = 0.0, offU = 0.0, totU = 0.0;
    #pragma unroll
    for (int w2 = 0; w2 < NWAVE; ++w2) {
        double a = wtA[w2], b = wtU[w2];
        if (w2 < wave) { offT += a; offU += b; }
        totU += b;
    }
    A0 = offT + baseT + tv0;
    A1 = A0 + tv1;
    double PU0 = offU + baseU + uv0;
    double PU1 = PU0 + uv1;
    B0 = totU - PU0;     // double precision: cancellation error ~1e-12 abs
    B1 = totU - PU1;
}

__device__ __forceinline__ double block_sum(double v, double* wsh, int lane, int wave)
{
    #pragma unroll
    for (int d = 32; d > 0; d >>= 1) v += __shfl_xor(v, d, 64);
    if (lane == 0) wsh[wave] = v;
    __syncthreads();
    double t = 0.0;
    #pragma unroll
    for (int w = 0; w < NWAVE; ++w) t += wsh[w];
    return t;
}

__global__ __launch_bounds__(NT) void sink_kernel(
    const float* __restrict__ s_g, const float* __restrict__ labp_g,
    const float* __restrict__ slab_g, float* __restrict__ out)
{
    __shared__ double ep[NN], em[NN];    // exp(+s), exp(-s) in sorted coords
    __shared__ double rr[NN], cc[NN];    // Sinkhorn scaling vectors
    __shared__ float  lab[NN];           // labels in sorted-score coords
    __shared__ double wtA[NWAVE], wtU[NWAVE], wmax[NWAVE], wsum[NWAVE];

    const int T = threadIdx.x;
    const int lane = T & 63, wave = T >> 6;
    const int k0 = 2 * T, k1 = 2 * T + 1;

    // ---- load + tables ----
    double idcg_local = 0.0;
    for (int k = T; k < NN; k += NT) {
        double sv = (double)s_g[k];
        ep[k] = exp(sv);
        em[k] = exp(-sv);
        lab[k] = labp_g[k];
        rr[k] = 1.0; cc[k] = 1.0;
        idcg_local += (double)slab_g[k] / log2((double)k + 2.0);
    }
    __syncthreads();
    double idcg = block_sum(idcg_local, wsum, lane, wave);   // uniform in regs

    double ep0 = ep[k0], ep1 = ep[k1], em0 = em[k0], em1 = em[k1];
    double A0, A1, B0, B1;

    // ---- init: row softmax denominators, r_i = 1/(K*1)_i, c = 1 ----
    phase_scan(em0, em1, ep0, ep1, wtA, wtU, lane, wave, A0, A1, B0, B1);
    rr[k0] = 1.0 / (ep0 * A0 + em0 * B0);
    rr[k1] = 1.0 / (ep1 * A1 + em1 * B1);
    __syncthreads();

    // ---- Sinkhorn loop: m = diag(r) K diag(c), phases update c then r ----
    for (int it = 1; it <= MAXIT; ++it) {
        // phase A: colsum_k = c_k * (K r)_k ; c /= max(colsum, eps)
        double r0 = rr[k0], r1 = rr[k1];
        phase_scan(em0 * r0, em1 * r1, ep0 * r0, ep1 * r1,
                   wtA, wtU, lane, wave, A0, A1, B0, B1);
        double cs0 = cc[k0] * (ep0 * A0 + em0 * B0);
        double cs1 = cc[k1] * (ep1 * A1 + em1 * B1);
        cc[k0] = cc[k0] / fmax(cs0, EPSD);
        cc[k1] = cc[k1] / fmax(cs1, EPSD);
        double dev = fmax(fabs(cs0 - 1.0), fabs(cs1 - 1.0));
        #pragma unroll
        for (int d = 32; d > 0; d >>= 1) dev = fmax(dev, __shfl_xor(dev, d, 64));
        if (lane == 0) wmax[wave] = dev;
        __syncthreads();

        bool stop = false;
        if (it >= 2) {   // colsum of matrix after iteration it-1 => its convergence
            double md = 0.0;
            #pragma unroll
            for (int w = 0; w < NWAVE; ++w) md = fmax(md, wmax[w]);
            stop = (md < TOLD);
        }

        // phase B: rowsum_i = r_i * (K c)_i ; r /= max(rowsum, eps)
        double c0 = cc[k0], c1 = cc[k1];
        phase_scan(em0 * c0, em1 * c1, ep0 * c0, ep1 * c1,
                   wtA, wtU, lane, wave, A0, A1, B0, B1);
        double rs0 = rr[k0] * (ep0 * A0 + em0 * B0);
        double rs1 = rr[k1] * (ep1 * A1 + em1 * B1);
        rr[k0] = rr[k0] / fmax(rs0, EPSD);
        rr[k1] = rr[k1] / fmax(rs1, EPSD);
        __syncthreads();
        if (stop) break;   // uniform decision; one extra norm past convergence
    }

    // ---- epilogue: dcg = sum_i r_i * (K (c.*lab))_i / log2(i+2) ----
    double g0 = cc[k0] * (double)lab[k0], g1 = cc[k1] * (double)lab[k1];
    phase_scan(em0 * g0, em1 * g1, ep0 * g0, ep1 * g1,
               wtA, wtU, lane, wave, A0, A1, B0, B1);
    double contrib = rr[k0] * (ep0 * A0 + em0 * B0) / log2((double)k0 + 2.0)
                   + rr[k1] * (ep1 * A1 + em1 * B1) / log2((double)k1 + 2.0);
    __syncthreads();   // protect wsum reuse
    double dcg = block_sum(contrib, wsum, lane, wave);

    if (T == 0) out[0] = (float)(1.0 - dcg / idcg);
}

extern "C" void kernel_launch(void* const* d_in, const int* in_sizes, int n_in,
                              void* d_out, int out_size, void* d_ws, size_t ws_size,
                              hipStream_t stream) {
    const float* y_pred = (const float*)d_in[0];
    const float* y_true = (const float*)d_in[1];
    float* out = (float*)d_out;
    float* ws  = (float*)d_ws;

    float* s    = ws;
    float* labp = ws + 2048;
    float* slab = ws + 4096;

    prep_kernel<<<16, 256, 0, stream>>>(y_pred, y_true, s, labp, slab);
    sink_kernel<<<1, NT, 0, stream>>>(s, labp, slab, out);
}

// Round 3
// 86.823 us; speedup vs baseline: 11.0949x; 2.2926x over previous
//
#include <hip/hip_runtime.h>
#include <math.h>

#define NN    2048
#define ST    512            // sink threads (8 waves)
#define SW    8
#define MAXIT 50
#define TOLF  1e-6f
#define EPSF  1e-10f

// ws float layout: [0,2048) s sorted-desc scores ; [2048,4096) labp labels in
// score-sorted coords ; [4096,6144) slab labels sorted desc.

// ---------------------------------------------------------------------------
// Kernel A: rank-count sorts. 64 blocks x 256 thr; 4 threads per element on a
// striped j-partition; comparisons run from LDS (broadcast-friendly b128).
// ---------------------------------------------------------------------------
__global__ __launch_bounds__(256) void prep_kernel(
    const float* __restrict__ y_pred, const float* __restrict__ y_true,
    float* __restrict__ s, float* __restrict__ labp, float* __restrict__ slab)
{
    __shared__ float buf[NN];
    const int T = threadIdx.x;
    const int b = blockIdx.x;
    const bool scores = (b < 32);
    const float* src = scores ? y_pred : y_true;

    float4* b4 = (float4*)buf;
    const float4* s4 = (const float4*)src;
    b4[T]       = s4[T];
    b4[T + 256] = s4[T + 256];
    __syncthreads();

    const int eloc = T >> 2;             // 0..63
    const int q    = T & 3;              // j-stripe
    const int e    = ((b & 31) << 6) + eloc;
    const float v  = buf[e];
    int rank = 0;
    #pragma unroll 8
    for (int m = 0; m < 128; ++m) {
        int f4i = (m << 2) + q;          // striped float4 index -> 4 consecutive
        float4 w = b4[f4i];              // 16B lines per wave instr, no conflicts
        int j = f4i << 2;
        rank += (w.x > v) || ((w.x == v) && (j     < e));
        rank += (w.y > v) || ((w.y == v) && (j + 1 < e));
        rank += (w.z > v) || ((w.z == v) && (j + 2 < e));
        rank += (w.w > v) || ((w.w == v) && (j + 3 < e));
    }
    rank += __shfl_xor(rank, 1, 64);
    rank += __shfl_xor(rank, 2, 64);
    if (q == 0) {
        if (scores) {
            s[rank]    = v;
            labp[rank] = exp2f(y_true[e]) - 1.0f;
        } else {
            slab[rank] = exp2f(v) - 1.0f;
        }
    }
}

// ---------------------------------------------------------------------------
// Kernel B: single-block Sinkhorn. K_ij = e^{-|s_i-s_j|} is symmetric and
// separable in sorted coords: (Kv)_i = ep_i * prefix(em.v)_i + em_i * suffix(ep.v)_i.
// f32 prefix (shfl_up) + direct f32 suffix (shfl_down): no cancellation.
// r,c in registers (thread owns 4 contiguous elements). 1 barrier per phase.
// ---------------------------------------------------------------------------
__device__ __forceinline__ void phase_scan(
    float t0, float t1, float t2, float t3,
    float u0, float u1, float u2, float u3,
    float* bufA, float* bufU, int lane, int wave,
    float& A0, float& A1, float& A2, float& A3,
    float& B0, float& B1, float& B2, float& B3)
{
    float Tp = (t0 + t1) + (t2 + t3);
    float Up = (u0 + u1) + (u2 + u3);
    float xt = Tp, xu = Up;
    #pragma unroll
    for (int d = 1; d < 64; d <<= 1) {
        float yt = __shfl_up(xt, (unsigned)d, 64);
        float yu = __shfl_down(xu, (unsigned)d, 64);
        if (lane >= d)     xt += yt;
        if (lane + d < 64) xu += yu;
    }
    if (lane == 63) bufA[wave] = xt;   // wave total of t
    if (lane == 0)  bufU[wave] = xu;   // wave total of u
    __syncthreads();
    float4 a0 = *(const float4*)&bufA[0];
    float4 a1 = *(const float4*)&bufA[4];
    float4 v0 = *(const float4*)&bufU[0];
    float4 v1 = *(const float4*)&bufU[4];
    float offT = 0.0f, offU = 0.0f;
    offT += (wave > 0) ? a0.x : 0.0f;
    offT += (wave > 1) ? a0.y : 0.0f;
    offT += (wave > 2) ? a0.z : 0.0f;
    offT += (wave > 3) ? a0.w : 0.0f;
    offT += (wave > 4) ? a1.x : 0.0f;
    offT += (wave > 5) ? a1.y : 0.0f;
    offT += (wave > 6) ? a1.z : 0.0f;
    offU += (wave < 1) ? v0.y : 0.0f;
    offU += (wave < 2) ? v0.z : 0.0f;
    offU += (wave < 3) ? v0.w : 0.0f;
    offU += (wave < 4) ? v1.x : 0.0f;
    offU += (wave < 5) ? v1.y : 0.0f;
    offU += (wave < 6) ? v1.z : 0.0f;
    offU += (wave < 7) ? v1.w : 0.0f;
    float baseT = offT + (xt - Tp);    // exclusive prefix before this thread
    float baseU = offU + (xu - Up);    // strict suffix after this thread
    A0 = baseT + t0; A1 = A0 + t1; A2 = A1 + t2; A3 = A2 + t3;
    B3 = baseU; B2 = B3 + u3; B1 = B2 + u2; B0 = B1 + u1;
}

__device__ __forceinline__ double block_sum_d(double v, double* dsh, int lane, int wave)
{
    #pragma unroll
    for (int d = 32; d > 0; d >>= 1) v += __shfl_xor(v, d, 64);
    if (lane == 0) dsh[wave] = v;
    __syncthreads();
    double t = 0.0;
    #pragma unroll
    for (int w = 0; w < SW; ++w) t += dsh[w];
    return t;
}

__global__ __launch_bounds__(ST) void sink_kernel(
    const float* __restrict__ s_g, const float* __restrict__ labp_g,
    const float* __restrict__ slab_g, float* __restrict__ out)
{
    __shared__ __align__(16) float wtA[2][SW];
    __shared__ __align__(16) float wtU[2][SW];
    __shared__ __align__(16) float wdev[SW];
    __shared__ double dsum[SW];

    const int T = threadIdx.x;
    const int lane = T & 63, wave = T >> 6;
    const int k0 = 4 * T;

    float4 sv = ((const float4*)s_g)[T];
    float ep0 = __expf(sv.x), ep1 = __expf(sv.y), ep2 = __expf(sv.z), ep3 = __expf(sv.w);
    float em0 = __expf(-sv.x), em1 = __expf(-sv.y), em2 = __expf(-sv.z), em3 = __expf(-sv.w);
    float4 lb = ((const float4*)labp_g)[T];
    float4 sl = ((const float4*)slab_g)[T];

    float d0 = log2f((float)(k0 + 2)), d1 = log2f((float)(k0 + 3));
    float d2 = log2f((float)(k0 + 4)), d3 = log2f((float)(k0 + 5));
    double idl = (double)(sl.x / d0) + (double)(sl.y / d1)
               + (double)(sl.z / d2) + (double)(sl.w / d3);
    double idcg = block_sum_d(idl, dsum, lane, wave);

    float A0, A1, A2, A3, B0, B1, B2, B3;
    int pb = 0;

    // init: r_i = 1 / (K*1)_i  (softmax denominator; rowmax of dist == 0 exactly)
    phase_scan(em0, em1, em2, em3, ep0, ep1, ep2, ep3,
               wtA[pb], wtU[pb], lane, wave, A0, A1, A2, A3, B0, B1, B2, B3);
    pb ^= 1;
    float r0 = __builtin_amdgcn_rcpf(ep0 * A0 + em0 * B0);
    float r1 = __builtin_amdgcn_rcpf(ep1 * A1 + em1 * B1);
    float r2 = __builtin_amdgcn_rcpf(ep2 * A2 + em2 * B2);
    float r3 = __builtin_amdgcn_rcpf(ep3 * A3 + em3 * B3);
    float c0 = 1.0f, c1 = 1.0f, c2 = 1.0f, c3 = 1.0f;

    for (int it = 1; it <= MAXIT; ++it) {
        // phase A: colsum_k = c_k * (K r)_k ; c /= clip(colsum)
        phase_scan(em0 * r0, em1 * r1, em2 * r2, em3 * r3,
                   ep0 * r0, ep1 * r1, ep2 * r2, ep3 * r3,
                   wtA[pb], wtU[pb], lane, wave, A0, A1, A2, A3, B0, B1, B2, B3);
        pb ^= 1;
        float cs0 = c0 * (ep0 * A0 + em0 * B0);
        float cs1 = c1 * (ep1 * A1 + em1 * B1);
        float cs2 = c2 * (ep2 * A2 + em2 * B2);
        float cs3 = c3 * (ep3 * A3 + em3 * B3);
        c0 *= __builtin_amdgcn_rcpf(fmaxf(cs0, EPSF));
        c1 *= __builtin_amdgcn_rcpf(fmaxf(cs1, EPSF));
        c2 *= __builtin_amdgcn_rcpf(fmaxf(cs2, EPSF));
        c3 *= __builtin_amdgcn_rcpf(fmaxf(cs3, EPSF));
        float dv = fmaxf(fmaxf(fabsf(cs0 - 1.0f), fabsf(cs1 - 1.0f)),
                         fmaxf(fabsf(cs2 - 1.0f), fabsf(cs3 - 1.0f)));
        #pragma unroll
        for (int d = 32; d > 0; d >>= 1) dv = fmaxf(dv, __shfl_xor(dv, d, 64));
        if (lane == 0) wdev[wave] = dv;    // lands before phase B's barrier

        // phase B: rowsum_k = r_k * (K c)_k ; r /= clip(rowsum)
        phase_scan(em0 * c0, em1 * c1, em2 * c2, em3 * c3,
                   ep0 * c0, ep1 * c1, ep2 * c2, ep3 * c3,
                   wtA[pb], wtU[pb], lane, wave, A0, A1, A2, A3, B0, B1, B2, B3);
        pb ^= 1;
        float rs0 = r0 * (ep0 * A0 + em0 * B0);
        float rs1 = r1 * (ep1 * A1 + em1 * B1);
        float rs2 = r2 * (ep2 * A2 + em2 * B2);
        float rs3 = r3 * (ep3 * A3 + em3 * B3);
        r0 *= __builtin_amdgcn_rcpf(fmaxf(rs0, EPSF));
        r1 *= __builtin_amdgcn_rcpf(fmaxf(rs1, EPSF));
        r2 *= __builtin_amdgcn_rcpf(fmaxf(rs2, EPSF));
        r3 *= __builtin_amdgcn_rcpf(fmaxf(rs3, EPSF));

        if (it >= 2) {   // convergence of m after (it-1) norms; read after B barrier
            float4 w0 = *(const float4*)&wdev[0];
            float4 w1 = *(const float4*)&wdev[4];
            float md = fmaxf(fmaxf(fmaxf(w0.x, w0.y), fmaxf(w0.z, w0.w)),
                             fmaxf(fmaxf(w1.x, w1.y), fmaxf(w1.z, w1.w)));
            if (md < TOLF) break;   // uniform; one extra norm past convergence
        }
    }

    // epilogue: dcg = sum_k r_k * (K (c.*lab))_k / log2(k+2)
    float g0 = c0 * lb.x, g1 = c1 * lb.y, g2 = c2 * lb.z, g3 = c3 * lb.w;
    phase_scan(em0 * g0, em1 * g1, em2 * g2, em3 * g3,
               ep0 * g0, ep1 * g1, ep2 * g2, ep3 * g3,
               wtA[pb], wtU[pb], lane, wave, A0, A1, A2, A3, B0, B1, B2, B3);
    double contrib = (double)(r0 * (ep0 * A0 + em0 * B0) / d0)
                   + (double)(r1 * (ep1 * A1 + em1 * B1) / d1)
                   + (double)(r2 * (ep2 * A2 + em2 * B2) / d2)
                   + (double)(r3 * (ep3 * A3 + em3 * B3) / d3);
    __syncthreads();
    double dcg = block_sum_d(contrib, dsum, lane, wave);

    if (T == 0) out[0] = (float)(1.0 - dcg / idcg);
}

extern "C" void kernel_launch(void* const* d_in, const int* in_sizes, int n_in,
                              void* d_out, int out_size, void* d_ws, size_t ws_size,
                              hipStream_t stream) {
    const float* y_pred = (const float*)d_in[0];
    const float* y_true = (const float*)d_in[1];
    float* out = (float*)d_out;
    float* ws  = (float*)d_ws;

    float* s    = ws;
    float* labp = ws + 2048;
    float* slab = ws + 4096;

    prep_kernel<<<64, 256, 0, stream>>>(y_pred, y_true, s, labp, slab);
    sink_kernel<<<1, ST, 0, stream>>>(s, labp, slab, out);
}

// Round 4
// 81.528 us; speedup vs baseline: 11.8156x; 1.0650x over previous
//
#include <hip/hip_runtime.h>
#include <math.h>

#define NN    2048
#define ST    512            // sink threads (8 waves)
#define SW    8
#define MAXIT 50
#define TOLF  1e-6f
#define EPSF  1e-10f

// ws float layout: [0,2048) s sorted-desc scores ; [2048,4096) labp labels in
// score-sorted coords ; [4096,6144) slab labels sorted desc.

// ---------------------------------------------------------------------------
// Kernel A: rank-count sorts. 64 blocks x 256 thr; 4 threads per element on a
// striped j-partition; comparisons run from LDS.
// ---------------------------------------------------------------------------
__global__ __launch_bounds__(256) void prep_kernel(
    const float* __restrict__ y_pred, const float* __restrict__ y_true,
    float* __restrict__ s, float* __restrict__ labp, float* __restrict__ slab)
{
    __shared__ float buf[NN];
    const int T = threadIdx.x;
    const int b = blockIdx.x;
    const bool scores = (b < 32);
    const float* src = scores ? y_pred : y_true;

    float4* b4 = (float4*)buf;
    const float4* s4 = (const float4*)src;
    b4[T]       = s4[T];
    b4[T + 256] = s4[T + 256];
    __syncthreads();

    const int eloc = T >> 2;             // 0..63
    const int q    = T & 3;              // j-stripe
    const int e    = ((b & 31) << 6) + eloc;
    const float v  = buf[e];
    int rank = 0;
    #pragma unroll 8
    for (int m = 0; m < 128; ++m) {
        int f4i = (m << 2) + q;
        float4 w = b4[f4i];
        int j = f4i << 2;
        rank += (w.x > v) || ((w.x == v) && (j     < e));
        rank += (w.y > v) || ((w.y == v) && (j + 1 < e));
        rank += (w.z > v) || ((w.z == v) && (j + 2 < e));
        rank += (w.w > v) || ((w.w == v) && (j + 3 < e));
    }
    rank += __shfl_xor(rank, 1, 64);
    rank += __shfl_xor(rank, 2, 64);
    if (q == 0) {
        if (scores) {
            s[rank]    = v;
            labp[rank] = exp2f(y_true[e]) - 1.0f;
        } else {
            slab[rank] = exp2f(v) - 1.0f;
        }
    }
}

// ---------------------------------------------------------------------------
// DPP helpers (VALU-pipe cross-lane; replaces ds_bpermute shfl chains)
// ---------------------------------------------------------------------------
template<int CTRL, int RMASK>
__device__ __forceinline__ float dpp_add(float x) {
    int y = __builtin_amdgcn_update_dpp(0, __float_as_int(x), CTRL, RMASK, 0xf, true);
    return x + __int_as_float(y);
}
template<int CTRL, int RMASK>
__device__ __forceinline__ float dpp_fmax(float x) {
    int y = __builtin_amdgcn_update_dpp(0, __float_as_int(x), CTRL, RMASK, 0xf, true);
    return fmaxf(x, __int_as_float(y));
}

// wave64 inclusive prefix sum (LLVM atomic-optimizer sequence)
__device__ __forceinline__ float wave_prefix(float x) {
    x = dpp_add<0x111, 0xf>(x);   // row_shr:1
    x = dpp_add<0x112, 0xf>(x);   // row_shr:2
    x = dpp_add<0x114, 0xf>(x);   // row_shr:4
    x = dpp_add<0x118, 0xf>(x);   // row_shr:8
    x = dpp_add<0x142, 0xa>(x);   // row_bcast15 -> rows 1,3
    x = dpp_add<0x143, 0xc>(x);   // row_bcast31 -> rows 2,3
    return x;                     // lane63 = wave total
}

// wave64 inclusive suffix sum: in-row row_shl scan + readlane cross-row combine
__device__ __forceinline__ float wave_suffix(float x, int lane) {
    x = dpp_add<0x101, 0xf>(x);   // row_shl:1
    x = dpp_add<0x102, 0xf>(x);   // row_shl:2
    x = dpp_add<0x104, 0xf>(x);   // row_shl:4
    x = dpp_add<0x108, 0xf>(x);   // row_shl:8
    // row suffix-totals now at lanes 0,16,32,48
    float U1 = __int_as_float(__builtin_amdgcn_readlane(__float_as_int(x), 16));
    float U2 = __int_as_float(__builtin_amdgcn_readlane(__float_as_int(x), 32));
    float U3 = __int_as_float(__builtin_amdgcn_readlane(__float_as_int(x), 48));
    int r = lane >> 4;
    float s23 = U2 + U3;
    float add = (r == 0) ? (U1 + s23) : (r == 1) ? s23 : (r == 2) ? U3 : 0.0f;
    return x + add;               // lane0 = wave total
}

// wave64 max; lane63 holds the full-wave max (values must be >= 0)
__device__ __forceinline__ float wave_max63(float x) {
    x = dpp_fmax<0x111, 0xf>(x);
    x = dpp_fmax<0x112, 0xf>(x);
    x = dpp_fmax<0x114, 0xf>(x);
    x = dpp_fmax<0x118, 0xf>(x);
    x = dpp_fmax<0x142, 0xa>(x);
    x = dpp_fmax<0x143, 0xc>(x);
    return x;
}

// ---------------------------------------------------------------------------
// Kernel B: single-block Sinkhorn. K_ij = e^{-|s_i-s_j|} separable in sorted
// coords: (Kv)_i = ep_i * prefix(em.v)_i + em_i * suffix(ep.v)_i.
// r,c in registers (thread owns 4 contiguous elems). 1 barrier per phase.
// ---------------------------------------------------------------------------
__device__ __forceinline__ void phase_scan(
    float t0, float t1, float t2, float t3,
    float u0, float u1, float u2, float u3,
    float2* wtot, int lane, int wave,
    float& A0, float& A1, float& A2, float& A3,
    float& B0, float& B1, float& B2, float& B3)
{
    float Tp = (t0 + t1) + (t2 + t3);
    float Up = (u0 + u1) + (u2 + u3);
    float xt = wave_prefix(Tp);
    float xu = wave_suffix(Up, lane);
    if (lane == 63) wtot[wave].x = xt;   // wave total of t
    if (lane == 0)  wtot[wave].y = xu;   // wave total of u
    __syncthreads();
    float4 q0 = *(const float4*)&wtot[0];   // {t0,u0,t1,u1}
    float4 q1 = *(const float4*)&wtot[2];   // {t2,u2,t3,u3}
    float4 q2 = *(const float4*)&wtot[4];   // {t4,u4,t5,u5}
    float4 q3 = *(const float4*)&wtot[6];   // {t6,u6,t7,u7}
    float offT = 0.0f, offU = 0.0f;
    offT += (wave > 0) ? q0.x : 0.0f;  offU += (wave < 1) ? q0.w : 0.0f;
    offT += (wave > 1) ? q0.z : 0.0f;  offU += (wave < 2) ? q1.y : 0.0f;
    offT += (wave > 2) ? q1.x : 0.0f;  offU += (wave < 3) ? q1.w : 0.0f;
    offT += (wave > 3) ? q1.z : 0.0f;  offU += (wave < 4) ? q2.y : 0.0f;
    offT += (wave > 4) ? q2.x : 0.0f;  offU += (wave < 5) ? q2.w : 0.0f;
    offT += (wave > 5) ? q2.z : 0.0f;  offU += (wave < 6) ? q3.y : 0.0f;
    offT += (wave > 6) ? q3.x : 0.0f;  offU += (wave < 7) ? q3.w : 0.0f;
    float baseT = offT + (xt - Tp);    // exclusive prefix before this thread
    float baseU = offU + (xu - Up);    // strict suffix after this thread
    A0 = baseT + t0; A1 = A0 + t1; A2 = A1 + t2; A3 = A2 + t3;
    B3 = baseU; B2 = B3 + u3; B1 = B2 + u2; B0 = B1 + u1;
}

__device__ __forceinline__ double block_sum_d(double v, double* dsh, int lane, int wave)
{
    #pragma unroll
    for (int d = 32; d > 0; d >>= 1) v += __shfl_xor(v, d, 64);
    if (lane == 0) dsh[wave] = v;
    __syncthreads();
    double t = 0.0;
    #pragma unroll
    for (int w = 0; w < SW; ++w) t += dsh[w];
    return t;
}

__global__ __launch_bounds__(ST) void sink_kernel(
    const float* __restrict__ s_g, const float* __restrict__ labp_g,
    const float* __restrict__ slab_g, float* __restrict__ out)
{
    __shared__ __align__(16) float2 wtot[2][SW];
    __shared__ __align__(16) float wdev[SW];
    __shared__ double dsum[SW];

    const int T = threadIdx.x;
    const int lane = T & 63, wave = T >> 6;
    const int k0 = 4 * T;

    float4 sv = ((const float4*)s_g)[T];
    float ep0 = __expf(sv.x), ep1 = __expf(sv.y), ep2 = __expf(sv.z), ep3 = __expf(sv.w);
    float em0 = __expf(-sv.x), em1 = __expf(-sv.y), em2 = __expf(-sv.z), em3 = __expf(-sv.w);
    float4 lb = ((const float4*)labp_g)[T];
    float4 sl = ((const float4*)slab_g)[T];

    float d0 = log2f((float)(k0 + 2)), d1 = log2f((float)(k0 + 3));
    float d2 = log2f((float)(k0 + 4)), d3 = log2f((float)(k0 + 5));
    double idl = (double)(sl.x / d0) + (double)(sl.y / d1)
               + (double)(sl.z / d2) + (double)(sl.w / d3);
    double idcg = block_sum_d(idl, dsum, lane, wave);

    float A0, A1, A2, A3, B0, B1, B2, B3;
    int pb = 0;

    // init: r_i = 1 / (K*1)_i  (softmax denominator; rowmax of dist == 0 exactly)
    phase_scan(em0, em1, em2, em3, ep0, ep1, ep2, ep3,
               wtot[pb], lane, wave, A0, A1, A2, A3, B0, B1, B2, B3);
    pb ^= 1;
    float r0 = __builtin_amdgcn_rcpf(ep0 * A0 + em0 * B0);
    float r1 = __builtin_amdgcn_rcpf(ep1 * A1 + em1 * B1);
    float r2 = __builtin_amdgcn_rcpf(ep2 * A2 + em2 * B2);
    float r3 = __builtin_amdgcn_rcpf(ep3 * A3 + em3 * B3);
    float c0 = 1.0f, c1 = 1.0f, c2 = 1.0f, c3 = 1.0f;

    for (int it = 1; it <= MAXIT; ++it) {
        // phase A: colsum_k = c_k * (K r)_k ; c /= clip(colsum)
        phase_scan(em0 * r0, em1 * r1, em2 * r2, em3 * r3,
                   ep0 * r0, ep1 * r1, ep2 * r2, ep3 * r3,
                   wtot[pb], lane, wave, A0, A1, A2, A3, B0, B1, B2, B3);
        pb ^= 1;
        float cs0 = c0 * (ep0 * A0 + em0 * B0);
        float cs1 = c1 * (ep1 * A1 + em1 * B1);
        float cs2 = c2 * (ep2 * A2 + em2 * B2);
        float cs3 = c3 * (ep3 * A3 + em3 * B3);
        c0 *= __builtin_amdgcn_rcpf(fmaxf(cs0, EPSF));
        c1 *= __builtin_amdgcn_rcpf(fmaxf(cs1, EPSF));
        c2 *= __builtin_amdgcn_rcpf(fmaxf(cs2, EPSF));
        c3 *= __builtin_amdgcn_rcpf(fmaxf(cs3, EPSF));
        float dv = fmaxf(fmaxf(fabsf(cs0 - 1.0f), fabsf(cs1 - 1.0f)),
                         fmaxf(fabsf(cs2 - 1.0f), fabsf(cs3 - 1.0f)));
        dv = wave_max63(dv);
        if (lane == 63) wdev[wave] = dv;   // visible after phase B's barrier

        // phase B: rowsum_k = r_k * (K c)_k ; r /= clip(rowsum)
        phase_scan(em0 * c0, em1 * c1, em2 * c2, em3 * c3,
                   ep0 * c0, ep1 * c1, ep2 * c2, ep3 * c3,
                   wtot[pb], lane, wave, A0, A1, A2, A3, B0, B1, B2, B3);
        pb ^= 1;
        float rs0 = r0 * (ep0 * A0 + em0 * B0);
        float rs1 = r1 * (ep1 * A1 + em1 * B1);
        float rs2 = r2 * (ep2 * A2 + em2 * B2);
        float rs3 = r3 * (ep3 * A3 + em3 * B3);
        r0 *= __builtin_amdgcn_rcpf(fmaxf(rs0, EPSF));
        r1 *= __builtin_amdgcn_rcpf(fmaxf(rs1, EPSF));
        r2 *= __builtin_amdgcn_rcpf(fmaxf(rs2, EPSF));
        r3 *= __builtin_amdgcn_rcpf(fmaxf(rs3, EPSF));

        if (it >= 2) {   // convergence of m after (it-1) norms
            float4 w0 = *(const float4*)&wdev[0];
            float4 w1 = *(const float4*)&wdev[4];
            float md = fmaxf(fmaxf(fmaxf(w0.x, w0.y), fmaxf(w0.z, w0.w)),
                             fmaxf(fmaxf(w1.x, w1.y), fmaxf(w1.z, w1.w)));
            if (md < TOLF) break;   // uniform; one extra norm past convergence
        }
    }

    // epilogue: dcg = sum_k r_k * (K (c.*lab))_k / log2(k+2)
    float g0 = c0 * lb.x, g1 = c1 * lb.y, g2 = c2 * lb.z, g3 = c3 * lb.w;
    phase_scan(em0 * g0, em1 * g1, em2 * g2, em3 * g3,
               ep0 * g0, ep1 * g1, ep2 * g2, ep3 * g3,
               wtot[pb], lane, wave, A0, A1, A2, A3, B0, B1, B2, B3);
    double contrib = (double)(r0 * (ep0 * A0 + em0 * B0) / d0)
                   + (double)(r1 * (ep1 * A1 + em1 * B1) / d1)
                   + (double)(r2 * (ep2 * A2 + em2 * B2) / d2)
                   + (double)(r3 * (ep3 * A3 + em3 * B3) / d3);
    __syncthreads();
    double dcg = block_sum_d(contrib, dsum, lane, wave);

    if (T == 0) out[0] = (float)(1.0 - dcg / idcg);
}

extern "C" void kernel_launch(void* const* d_in, const int* in_sizes, int n_in,
                              void* d_out, int out_size, void* d_ws, size_t ws_size,
                              hipStream_t stream) {
    const float* y_pred = (const float*)d_in[0];
    const float* y_true = (const float*)d_in[1];
    float* out = (float*)d_out;
    float* ws  = (float*)d_ws;

    float* s    = ws;
    float* labp = ws + 2048;
    float* slab = ws + 4096;

    prep_kernel<<<64, 256, 0, stream>>>(y_pred, y_true, s, labp, slab);
    sink_kernel<<<1, ST, 0, stream>>>(s, labp, slab, out);
}